// Round 4
// baseline (558.118 us; speedup 1.0000x reference)
//
#include <hip/hip_runtime.h>
#include <math.h>

#define NN 100000
#define NE 1600000
#define ET (NE + NN)
#define NK (NN * 8)            // chunked CSR keys: dst*8 + (src>>14)
#define SCAN_BLK 4096          // elements per scan1 block

__device__ inline unsigned short f2bf(float f) {            // RNE float->bf16
  union { float f; unsigned u; } v; v.f = f;
  unsigned r = v.u + 0x7fffu + ((v.u >> 16) & 1u);
  return (unsigned short)(r >> 16);
}
__device__ inline float bflo(unsigned u) { union { unsigned u; float f; } v; v.u = u << 16; return v.f; }
__device__ inline float bfhi(unsigned u) { union { unsigned u; float f; } v; v.u = u & 0xffff0000u; return v.f; }

// ---------------- CSR build (src-chunk-sorted within each dst bucket) ----------------
__global__ __launch_bounds__(256) void k_hist(const int* __restrict__ src, const int* __restrict__ dst,
                                              int* __restrict__ counts, int* __restrict__ slots) {
  int i = blockIdx.x * 256 + threadIdx.x;
  if (i >= ET) return;
  int d, s;
  if (i < NE) { d = dst[i]; s = src[i]; } else { d = i - NE; s = d; }
  slots[i] = atomicAdd(&counts[d * 8 + (s >> 14)], 1);
}

__global__ __launch_bounds__(256) void k_scan1(const int* __restrict__ counts, int* __restrict__ partial,
                                               int* __restrict__ blksum) {
  __shared__ int lds[256];
  int b = blockIdx.x, t = threadIdx.x;
  int base = b * SCAN_BLK + t * 16;
  int v[16];
  int s = 0;
#pragma unroll
  for (int j = 0; j < 16; j++) {
    int x = (base + j < NK) ? counts[base + j] : 0;
    s += x; v[j] = s;                                  // inclusive within thread
  }
  lds[t] = s; __syncthreads();
  int tot = s;
  for (int off = 1; off < 256; off <<= 1) {
    int u = 0; if (t >= off) u = lds[t - off];
    __syncthreads(); lds[t] += u; __syncthreads();
  }
  int pre = lds[t] - tot;
#pragma unroll
  for (int j = 0; j < 16; j++) if (base + j < NK) partial[base + j] = pre + v[j];
  if (t == 255) blksum[b] = lds[255];
}

__global__ __launch_bounds__(256) void k_scan2(int* __restrict__ blksum, int nb) {
  __shared__ int lds[256];
  int t = threadIdx.x;
  int v = (t < nb) ? blksum[t] : 0;
  lds[t] = v; __syncthreads();
  for (int off = 1; off < 256; off <<= 1) {
    int u = 0; if (t >= off) u = lds[t - off];
    __syncthreads(); lds[t] += u; __syncthreads();
  }
  if (t < nb) blksum[t] = lds[t] - v;   // exclusive block offsets
}

__global__ __launch_bounds__(256) void k_scan3(const int* __restrict__ partial, const int* __restrict__ blksum,
                                               int* __restrict__ rowptr) {
  int i = blockIdx.x * 256 + threadIdx.x;
  if (i >= NK) return;
  rowptr[i + 1] = partial[i] + blksum[i / SCAN_BLK];
  if (i == 0) rowptr[0] = 0;
}

__global__ __launch_bounds__(256) void k_scatter(const int* __restrict__ src, const int* __restrict__ dst,
                                                 const int* __restrict__ rowptr, const int* __restrict__ slots,
                                                 int* __restrict__ esrc) {
  int i = blockIdx.x * 256 + threadIdx.x;
  if (i >= ET) return;
  int d, s;
  if (i < NE) { d = dst[i]; s = src[i]; } else { d = i - NE; s = d; }
  esrc[rowptr[d * 8 + (s >> 14)] + slots[i]] = s;
}

// ---------------- register-tiled GEMM (h = X @ W) + fused alpha epilogue ----------------
// X: NN x 128 (fp32 or bf16 per XBF). W: 128 x M row-major fp32. Hf: NN x M bf16.
// Block: 64 rows x M cols, 256 threads, thread = 4 rows x (M/16) cols.
template<int M, bool XBF>
__global__ __launch_bounds__(256) void k_gemm(const float* __restrict__ Xf, const unsigned short* __restrict__ Xb,
                                              const float* __restrict__ W,
                                              const float* __restrict__ a_src, const float* __restrict__ a_dst,
                                              unsigned short* __restrict__ Hf, float* __restrict__ as_, float* __restrict__ ad_) {
  constexpr int CPT = M / 16;          // cols per thread: 8 (M=128) / 4 (M=64)
  __shared__ float xs[64 * 36];        // x tile [64 rows][32 k] stride 36
  __shared__ float ws[32 * M];         // w tile [32 k][M cols]
  const int t = threadIdx.x;
  const int tx = t & 15, ty = t >> 4;
  const int row0 = blockIdx.x * 64;
  const int c0 = tx * CPT;
  float acc[4][CPT];
#pragma unroll
  for (int i = 0; i < 4; i++)
#pragma unroll
    for (int j = 0; j < CPT; j++) acc[i][j] = 0.f;

  for (int st = 0; st < 4; ++st) {
    const int k0 = st * 32;
    __syncthreads();
    if constexpr (!XBF) {
      // stage X tile fp32: 64x32 floats = 512 float4, 2 per thread
#pragma unroll
      for (int j = 0; j < 2; ++j) {
        int flat = t + j * 256;
        int r = flat >> 3, c4 = (flat & 7) * 4;
        float4 v = make_float4(0.f, 0.f, 0.f, 0.f);
        if (row0 + r < NN) v = *(const float4*)(Xf + (size_t)(row0 + r) * 128 + k0 + c4);
        *(float4*)(xs + r * 36 + c4) = v;
      }
    } else {
      // stage X tile bf16: thread loads 8 bf16 (16B), converts to fp32
      int r = t >> 2, c8 = (t & 3) * 8;
      uint4 v = make_uint4(0, 0, 0, 0);
      if (row0 + r < NN) v = *(const uint4*)(Xb + (size_t)(row0 + r) * 128 + k0 + c8);
      float* d = xs + r * 36 + c8;
      d[0] = bflo(v.x); d[1] = bfhi(v.x); d[2] = bflo(v.y); d[3] = bfhi(v.y);
      d[4] = bflo(v.z); d[5] = bfhi(v.z); d[6] = bflo(v.w); d[7] = bfhi(v.w);
    }
    // stage W tile: 32xM floats
#pragma unroll
    for (int j = 0; j < M / 32; ++j) {
      int flat = t + j * 256;
      int r = flat / (M / 4), c4 = (flat % (M / 4)) * 4;
      *(float4*)(ws + r * M + c4) = *(const float4*)(W + (size_t)(k0 + r) * M + c4);
    }
    __syncthreads();
#pragma unroll
    for (int kk = 0; kk < 32; kk += 4) {
      float4 xv[4];
#pragma unroll
      for (int i = 0; i < 4; ++i) xv[i] = *(const float4*)(xs + (ty * 4 + i) * 36 + kk);
#pragma unroll
      for (int j = 0; j < 4; ++j) {
#pragma unroll
        for (int cc = 0; cc < CPT; cc += 4) {
          float4 wv = *(const float4*)(ws + (kk + j) * M + c0 + cc);
#pragma unroll
          for (int i = 0; i < 4; ++i) {
            float xx = ((const float*)&xv[i])[j];
            acc[i][cc + 0] += xx * wv.x;
            acc[i][cc + 1] += xx * wv.y;
            acc[i][cc + 2] += xx * wv.z;
            acc[i][cc + 3] += xx * wv.w;
          }
        }
      }
    }
  }

  // fused attention dots: alpha_src/alpha_dst per (row, head)
  float s1[4], s2[4];
#pragma unroll
  for (int i = 0; i < 4; ++i) {
    float a = 0.f, b = 0.f;
#pragma unroll
    for (int j = 0; j < CPT; ++j) { a += acc[i][j] * a_src[c0 + j]; b += acc[i][j] * a_dst[c0 + j]; }
    s1[i] = a; s2[i] = b;
  }
  if constexpr (M == 128) {
#pragma unroll
    for (int i = 0; i < 4; ++i) { s1[i] += __shfl_xor(s1[i], 1); s2[i] += __shfl_xor(s2[i], 1); }
  } else {
#pragma unroll
    for (int off = 1; off < 16; off <<= 1)
#pragma unroll
      for (int i = 0; i < 4; ++i) { s1[i] += __shfl_xor(s1[i], off); s2[i] += __shfl_xor(s2[i], off); }
  }
#pragma unroll
  for (int i = 0; i < 4; ++i) {
    int r = row0 + ty * 4 + i;
    if (r < NN) {
      if constexpr (M == 128) {
        uint4 pk;
        pk.x = (unsigned)f2bf(acc[i][0]) | ((unsigned)f2bf(acc[i][1]) << 16);
        pk.y = (unsigned)f2bf(acc[i][2]) | ((unsigned)f2bf(acc[i][3]) << 16);
        pk.z = (unsigned)f2bf(acc[i][4]) | ((unsigned)f2bf(acc[i][5]) << 16);
        pk.w = (unsigned)f2bf(acc[i][6]) | ((unsigned)f2bf(acc[i][7]) << 16);
        *(uint4*)(Hf + (size_t)r * M + c0) = pk;
        if ((tx & 1) == 0) { as_[r * 8 + (tx >> 1)] = s1[i]; ad_[r * 8 + (tx >> 1)] = s2[i]; }
      } else {
        uint2 pk;
        pk.x = (unsigned)f2bf(acc[i][0]) | ((unsigned)f2bf(acc[i][1]) << 16);
        pk.y = (unsigned)f2bf(acc[i][2]) | ((unsigned)f2bf(acc[i][3]) << 16);
        *(uint2*)(Hf + (size_t)r * M + c0) = pk;
        if (tx == 0) { as_[r] = s1[i]; ad_[r] = s2[i]; }
      }
    }
  }
}

// ---------------- per-destination online-softmax aggregation + bias + ELU ----------------
// one thread per (node, 4-channel quad); gathers bf16 h rows; output bf16 (or fused final linear)
template<int HH, int C, bool FINAL>
__global__ __launch_bounds__(256) void k_aggregate(const unsigned short* __restrict__ Hf, const float* __restrict__ as_,
                                                   const float* __restrict__ ad_, const int* __restrict__ rowptr,
                                                   const int* __restrict__ esrc, const float* __restrict__ bias,
                                                   const float* __restrict__ Wout, const float* __restrict__ bout,
                                                   unsigned short* __restrict__ outb, float* __restrict__ outf) {
  constexpr int CT = HH * C;
  constexpr int Q = CT / 4;
  int g = blockIdx.x * 256 + threadIdx.x;
  if (g >= NN * Q) return;
  int node = g / Q;
  int q = g - node * Q;
  int c = q * 4;
  int hh = c / C;
  int i0 = rowptr[node * 8], i1 = rowptr[node * 8 + 8];
  float ad = ad_[node * HH + hh];
  float m = -INFINITY, den = 0.f;
  float4 acc = make_float4(0.f, 0.f, 0.f, 0.f);
  for (int i = i0; i < i1; i++) {
    int s = esrc[i];
    float e = as_[s * HH + hh] + ad;
    e = e > 0.f ? e : 0.2f * e;                       // leaky_relu(0.2)
    float nm = fmaxf(m, e);
    float sc = __expf(m - nm);                        // exp(-inf)=0 handles first iter
    float p  = __expf(e - nm);
    uint2 hr = *(const uint2*)(Hf + (size_t)s * CT + c);
    den = den * sc + p;
    acc.x = acc.x * sc + p * bflo(hr.x);
    acc.y = acc.y * sc + p * bfhi(hr.x);
    acc.z = acc.z * sc + p * bflo(hr.y);
    acc.w = acc.w * sc + p * bfhi(hr.y);
    m = nm;
  }
  float inv = 1.f / den;
  float4 o;
  o.x = acc.x * inv + bias[c + 0];
  o.y = acc.y * inv + bias[c + 1];
  o.z = acc.z * inv + bias[c + 2];
  o.w = acc.w * inv + bias[c + 3];
  o.x = o.x > 0.f ? o.x : __expf(o.x) - 1.f;          // ELU
  o.y = o.y > 0.f ? o.y : __expf(o.y) - 1.f;
  o.z = o.z > 0.f ? o.z : __expf(o.z) - 1.f;
  o.w = o.w > 0.f ? o.w : __expf(o.w) - 1.f;
  if constexpr (!FINAL) {
    uint2 pk;
    pk.x = (unsigned)f2bf(o.x) | ((unsigned)f2bf(o.y) << 16);
    pk.y = (unsigned)f2bf(o.z) | ((unsigned)f2bf(o.w) << 16);
    *(uint2*)(outb + (size_t)node * CT + c) = pk;
  } else {
    // fused out = elu(h3) @ Wout + bout ; reduce over the node's 16 lanes
    float p0 = o.x * Wout[(c + 0) * 2 + 0] + o.y * Wout[(c + 1) * 2 + 0]
             + o.z * Wout[(c + 2) * 2 + 0] + o.w * Wout[(c + 3) * 2 + 0];
    float p1 = o.x * Wout[(c + 0) * 2 + 1] + o.y * Wout[(c + 1) * 2 + 1]
             + o.z * Wout[(c + 2) * 2 + 1] + o.w * Wout[(c + 3) * 2 + 1];
#pragma unroll
    for (int off = 1; off < 16; off <<= 1) { p0 += __shfl_xor(p0, off); p1 += __shfl_xor(p1, off); }
    if (q == 0) { outf[node * 2 + 0] = p0 + bout[0]; outf[node * 2 + 1] = p1 + bout[1]; }
  }
}

extern "C" void kernel_launch(void* const* d_in, const int* in_sizes, int n_in,
                              void* d_out, int out_size, void* d_ws, size_t ws_size,
                              hipStream_t stream) {
  const float* x    = (const float*)d_in[0];
  const int*   ei   = (const int*)d_in[1];
  const float* W1   = (const float*)d_in[2];
  const float* as1  = (const float*)d_in[3];
  const float* ad1  = (const float*)d_in[4];
  const float* b1   = (const float*)d_in[5];
  const float* W2   = (const float*)d_in[6];
  const float* as2  = (const float*)d_in[7];
  const float* ad2  = (const float*)d_in[8];
  const float* b2   = (const float*)d_in[9];
  const float* W3   = (const float*)d_in[10];
  const float* as3  = (const float*)d_in[11];
  const float* ad3  = (const float*)d_in[12];
  const float* b3   = (const float*)d_in[13];
  const float* Wout = (const float*)d_in[14];
  const float* bout = (const float*)d_in[15];
  const int* srcp = ei;
  const int* dstp = ei + NE;

  char* p = (char*)d_ws;
  auto alloc = [&](size_t bytes) { char* r = p; p += (bytes + 255) & ~size_t(255); return r; };
  int*            rowptr  = (int*)alloc((size_t)(NK + 1) * 4);
  int*            counts  = (int*)alloc((size_t)NK * 4);
  int*            partial = (int*)alloc((size_t)NK * 4);
  int*            blksum  = (int*)alloc(256 * 4);
  int*            esrc    = (int*)alloc((size_t)ET * 4);
  int*            slots   = (int*)alloc((size_t)ET * 4);
  float*          asb     = (float*)alloc((size_t)NN * 8 * 4);
  float*          adb     = (float*)alloc((size_t)NN * 8 * 4);
  unsigned short* hfb     = (unsigned short*)alloc((size_t)NN * 128 * 2);   // bf16 gather table
  unsigned short* actb    = (unsigned short*)alloc((size_t)NN * 128 * 2);   // bf16 activations

  hipMemsetAsync(counts, 0, (size_t)NK * 4, stream);
  int gE = (ET + 255) / 256;
  int nb = (NK + SCAN_BLK - 1) / SCAN_BLK;   // 196 <= 256
  k_hist<<<gE, 256, 0, stream>>>(srcp, dstp, counts, slots);
  k_scan1<<<nb, 256, 0, stream>>>(counts, partial, blksum);
  k_scan2<<<1, 256, 0, stream>>>(blksum, nb);
  k_scan3<<<(NK + 255) / 256, 256, 0, stream>>>(partial, blksum, rowptr);
  k_scatter<<<gE, 256, 0, stream>>>(srcp, dstp, rowptr, slots, esrc);

  int gGemm = (NN + 63) / 64;
  // layer 1: 128 -> 8x16, concat, ELU
  k_gemm<128, false><<<gGemm, 256, 0, stream>>>(x, nullptr, W1, as1, ad1, hfb, asb, adb);
  k_aggregate<8, 16, false><<<(NN * 32 + 255) / 256, 256, 0, stream>>>(hfb, asb, adb, rowptr, esrc, b1, nullptr, nullptr, actb, nullptr);
  // layer 2
  k_gemm<128, true><<<gGemm, 256, 0, stream>>>(nullptr, actb, W2, as2, ad2, hfb, asb, adb);
  k_aggregate<8, 16, false><<<(NN * 32 + 255) / 256, 256, 0, stream>>>(hfb, asb, adb, rowptr, esrc, b2, nullptr, nullptr, actb, nullptr);
  // layer 3: 128 -> 1x64, mean(=identity), ELU, fused 64->2 output linear
  k_gemm<64, true><<<gGemm, 256, 0, stream>>>(nullptr, actb, W3, as3, ad3, hfb, asb, adb);
  k_aggregate<1, 64, true><<<(NN * 16 + 255) / 256, 256, 0, stream>>>(hfb, asb, adb, rowptr, esrc, b3, Wout, bout, nullptr, (float*)d_out);
}

// Round 5
// 466.040 us; speedup vs baseline: 1.1976x; 1.1976x over previous
//
#include <hip/hip_runtime.h>
#include <math.h>

#define NN 100000
#define NE 1600000
#define ET (NE + NN)
#define SCAN_BLK 4096          // elements per scan1 block

__device__ inline unsigned short f2bf(float f) {            // RNE float->bf16
  union { float f; unsigned u; } v; v.f = f;
  unsigned r = v.u + 0x7fffu + ((v.u >> 16) & 1u);
  return (unsigned short)(r >> 16);
}
__device__ inline float bflo(unsigned u) { union { unsigned u; float f; } v; v.u = u << 16; return v.f; }
__device__ inline float bfhi(unsigned u) { union { unsigned u; float f; } v; v.u = u & 0xffff0000u; return v.f; }

// ---------------- CSR build ----------------
__global__ __launch_bounds__(256) void k_hist(const int* __restrict__ dst, int* __restrict__ counts,
                                              int* __restrict__ slots) {
  int i = blockIdx.x * 256 + threadIdx.x;
  if (i >= ET) return;
  int d = (i < NE) ? dst[i] : (i - NE);
  slots[i] = atomicAdd(&counts[d], 1);
}

__global__ __launch_bounds__(256) void k_scan1(const int* __restrict__ counts, int* __restrict__ partial,
                                               int* __restrict__ blksum) {
  __shared__ int lds[256];
  int b = blockIdx.x, t = threadIdx.x;
  int base = b * SCAN_BLK + t * 16;
  int v[16];
  int s = 0;
#pragma unroll
  for (int j = 0; j < 16; j++) {
    int x = (base + j < NN) ? counts[base + j] : 0;
    s += x; v[j] = s;                                  // inclusive within thread
  }
  lds[t] = s; __syncthreads();
  int tot = s;
  for (int off = 1; off < 256; off <<= 1) {
    int u = 0; if (t >= off) u = lds[t - off];
    __syncthreads(); lds[t] += u; __syncthreads();
  }
  int pre = lds[t] - tot;
#pragma unroll
  for (int j = 0; j < 16; j++) if (base + j < NN) partial[base + j] = pre + v[j];
  if (t == 255) blksum[b] = lds[255];
}

__global__ __launch_bounds__(256) void k_scan2(int* __restrict__ blksum, int nb) {
  __shared__ int lds[256];
  int t = threadIdx.x;
  int v = (t < nb) ? blksum[t] : 0;
  lds[t] = v; __syncthreads();
  for (int off = 1; off < 256; off <<= 1) {
    int u = 0; if (t >= off) u = lds[t - off];
    __syncthreads(); lds[t] += u; __syncthreads();
  }
  if (t < nb) blksum[t] = lds[t] - v;   // exclusive block offsets
}

__global__ __launch_bounds__(256) void k_scan3(const int* __restrict__ partial, const int* __restrict__ blksum,
                                               int* __restrict__ rowptr) {
  int i = blockIdx.x * 256 + threadIdx.x;
  if (i >= NN) return;
  rowptr[i + 1] = partial[i] + blksum[i / SCAN_BLK];
  if (i == 0) rowptr[0] = 0;
}

__global__ __launch_bounds__(256) void k_scatter(const int* __restrict__ src, const int* __restrict__ dst,
                                                 const int* __restrict__ rowptr, const int* __restrict__ slots,
                                                 int* __restrict__ esrc) {
  int i = blockIdx.x * 256 + threadIdx.x;
  if (i >= ET) return;
  int d, s;
  if (i < NE) { d = dst[i]; s = src[i]; } else { d = i - NE; s = d; }
  esrc[rowptr[d] + slots[i]] = s;
}

// ---------------- register-tiled GEMM (h = X @ W) + fused alpha epilogue ----------------
// X: NN x 128 (fp32 or bf16 per XBF). W: 128 x M row-major fp32. Hf: NN x M bf16.
// Block: 64 rows x M cols, 256 threads, thread = 4 rows x (M/16) cols.
template<int M, bool XBF>
__global__ __launch_bounds__(256) void k_gemm(const float* __restrict__ Xf, const unsigned short* __restrict__ Xb,
                                              const float* __restrict__ W,
                                              const float* __restrict__ a_src, const float* __restrict__ a_dst,
                                              unsigned short* __restrict__ Hf, float* __restrict__ as_, float* __restrict__ ad_) {
  constexpr int CPT = M / 16;          // cols per thread: 8 (M=128) / 4 (M=64)
  __shared__ float xs[64 * 36];        // x tile [64 rows][32 k] stride 36
  __shared__ float ws[32 * M];         // w tile [32 k][M cols]
  const int t = threadIdx.x;
  const int tx = t & 15, ty = t >> 4;
  const int row0 = blockIdx.x * 64;
  const int c0 = tx * CPT;
  float acc[4][CPT];
#pragma unroll
  for (int i = 0; i < 4; i++)
#pragma unroll
    for (int j = 0; j < CPT; j++) acc[i][j] = 0.f;

  for (int st = 0; st < 4; ++st) {
    const int k0 = st * 32;
    __syncthreads();
    if constexpr (!XBF) {
#pragma unroll
      for (int j = 0; j < 2; ++j) {
        int flat = t + j * 256;
        int r = flat >> 3, c4 = (flat & 7) * 4;
        float4 v = make_float4(0.f, 0.f, 0.f, 0.f);
        if (row0 + r < NN) v = *(const float4*)(Xf + (size_t)(row0 + r) * 128 + k0 + c4);
        *(float4*)(xs + r * 36 + c4) = v;
      }
    } else {
      int r = t >> 2, c8 = (t & 3) * 8;
      uint4 v = make_uint4(0, 0, 0, 0);
      if (row0 + r < NN) v = *(const uint4*)(Xb + (size_t)(row0 + r) * 128 + k0 + c8);
      float* d = xs + r * 36 + c8;
      d[0] = bflo(v.x); d[1] = bfhi(v.x); d[2] = bflo(v.y); d[3] = bfhi(v.y);
      d[4] = bflo(v.z); d[5] = bfhi(v.z); d[6] = bflo(v.w); d[7] = bfhi(v.w);
    }
#pragma unroll
    for (int j = 0; j < M / 32; ++j) {
      int flat = t + j * 256;
      int r = flat / (M / 4), c4 = (flat % (M / 4)) * 4;
      *(float4*)(ws + r * M + c4) = *(const float4*)(W + (size_t)(k0 + r) * M + c4);
    }
    __syncthreads();
#pragma unroll
    for (int kk = 0; kk < 32; kk += 4) {
      float4 xv[4];
#pragma unroll
      for (int i = 0; i < 4; ++i) xv[i] = *(const float4*)(xs + (ty * 4 + i) * 36 + kk);
#pragma unroll
      for (int j = 0; j < 4; ++j) {
#pragma unroll
        for (int cc = 0; cc < CPT; cc += 4) {
          float4 wv = *(const float4*)(ws + (kk + j) * M + c0 + cc);
#pragma unroll
          for (int i = 0; i < 4; ++i) {
            float xx = ((const float*)&xv[i])[j];
            acc[i][cc + 0] += xx * wv.x;
            acc[i][cc + 1] += xx * wv.y;
            acc[i][cc + 2] += xx * wv.z;
            acc[i][cc + 3] += xx * wv.w;
          }
        }
      }
    }
  }

  // fused attention dots: alpha_src/alpha_dst per (row, head)
  float s1[4], s2[4];
#pragma unroll
  for (int i = 0; i < 4; ++i) {
    float a = 0.f, b = 0.f;
#pragma unroll
    for (int j = 0; j < CPT; ++j) { a += acc[i][j] * a_src[c0 + j]; b += acc[i][j] * a_dst[c0 + j]; }
    s1[i] = a; s2[i] = b;
  }
  if constexpr (M == 128) {
#pragma unroll
    for (int i = 0; i < 4; ++i) { s1[i] += __shfl_xor(s1[i], 1); s2[i] += __shfl_xor(s2[i], 1); }
  } else {
#pragma unroll
    for (int off = 1; off < 16; off <<= 1)
#pragma unroll
      for (int i = 0; i < 4; ++i) { s1[i] += __shfl_xor(s1[i], off); s2[i] += __shfl_xor(s2[i], off); }
  }
#pragma unroll
  for (int i = 0; i < 4; ++i) {
    int r = row0 + ty * 4 + i;
    if (r < NN) {
      if constexpr (M == 128) {
        uint4 pk;
        pk.x = (unsigned)f2bf(acc[i][0]) | ((unsigned)f2bf(acc[i][1]) << 16);
        pk.y = (unsigned)f2bf(acc[i][2]) | ((unsigned)f2bf(acc[i][3]) << 16);
        pk.z = (unsigned)f2bf(acc[i][4]) | ((unsigned)f2bf(acc[i][5]) << 16);
        pk.w = (unsigned)f2bf(acc[i][6]) | ((unsigned)f2bf(acc[i][7]) << 16);
        *(uint4*)(Hf + (size_t)r * M + c0) = pk;
        if ((tx & 1) == 0) { as_[r * 8 + (tx >> 1)] = s1[i]; ad_[r * 8 + (tx >> 1)] = s2[i]; }
      } else {
        uint2 pk;
        pk.x = (unsigned)f2bf(acc[i][0]) | ((unsigned)f2bf(acc[i][1]) << 16);
        pk.y = (unsigned)f2bf(acc[i][2]) | ((unsigned)f2bf(acc[i][3]) << 16);
        *(uint2*)(Hf + (size_t)r * M + c0) = pk;
        if (tx == 0) { as_[r] = s1[i]; ad_[r] = s2[i]; }
      }
    }
  }
}

// ---------------- per-destination online-softmax aggregation, 2-way ILP ----------------
// one thread per (node, 4-channel quad); two independent softmax chains (even/odd edges)
template<int HH, int C, bool FINAL>
__global__ __launch_bounds__(256) void k_aggregate(const unsigned short* __restrict__ Hf, const float* __restrict__ as_,
                                                   const float* __restrict__ ad_, const int* __restrict__ rowptr,
                                                   const int* __restrict__ esrc, const float* __restrict__ bias,
                                                   const float* __restrict__ Wout, const float* __restrict__ bout,
                                                   unsigned short* __restrict__ outb, float* __restrict__ outf) {
  constexpr int CT = HH * C;
  constexpr int Q = CT / 4;
  int g = blockIdx.x * 256 + threadIdx.x;
  if (g >= NN * Q) return;
  int node = g / Q;
  int q = g - node * Q;
  int c = q * 4;
  int hh = c / C;
  int i0 = rowptr[node], i1 = rowptr[node + 1];
  float ad = ad_[node * HH + hh];
  float m0 = -INFINITY, d0 = 0.f;
  float m1 = -INFINITY, d1 = 0.f;
  float4 a0 = make_float4(0.f, 0.f, 0.f, 0.f);
  float4 a1 = make_float4(0.f, 0.f, 0.f, 0.f);
  int i = i0;
  for (; i + 1 < i1; i += 2) {
    int sA = esrc[i], sB = esrc[i + 1];
    float eA = as_[sA * HH + hh] + ad;
    float eB = as_[sB * HH + hh] + ad;
    uint2 hA = *(const uint2*)(Hf + (size_t)sA * CT + c);
    uint2 hB = *(const uint2*)(Hf + (size_t)sB * CT + c);
    eA = fmaxf(eA, 0.2f * eA);                        // leaky_relu(0.2), branchless
    eB = fmaxf(eB, 0.2f * eB);
    float nmA = fmaxf(m0, eA), nmB = fmaxf(m1, eB);
    float scA = __expf(m0 - nmA), scB = __expf(m1 - nmB);
    float pA = __expf(eA - nmA), pB = __expf(eB - nmB);
    d0 = d0 * scA + pA;                 d1 = d1 * scB + pB;
    a0.x = a0.x * scA + pA * bflo(hA.x); a1.x = a1.x * scB + pB * bflo(hB.x);
    a0.y = a0.y * scA + pA * bfhi(hA.x); a1.y = a1.y * scB + pB * bfhi(hB.x);
    a0.z = a0.z * scA + pA * bflo(hA.y); a1.z = a1.z * scB + pB * bflo(hB.y);
    a0.w = a0.w * scA + pA * bfhi(hA.y); a1.w = a1.w * scB + pB * bfhi(hB.y);
    m0 = nmA; m1 = nmB;
  }
  if (i < i1) {                                       // tail edge -> chain A
    int sA = esrc[i];
    float eA = as_[sA * HH + hh] + ad;
    uint2 hA = *(const uint2*)(Hf + (size_t)sA * CT + c);
    eA = fmaxf(eA, 0.2f * eA);
    float nmA = fmaxf(m0, eA);
    float scA = __expf(m0 - nmA);
    float pA = __expf(eA - nmA);
    d0 = d0 * scA + pA;
    a0.x = a0.x * scA + pA * bflo(hA.x);
    a0.y = a0.y * scA + pA * bfhi(hA.x);
    a0.z = a0.z * scA + pA * bflo(hA.y);
    a0.w = a0.w * scA + pA * bfhi(hA.y);
    m0 = nmA;
  }
  // merge the two chains (exp(-inf)=0 handles an empty chain B)
  float mm = fmaxf(m0, m1);
  float s0 = __expf(m0 - mm), s1v = __expf(m1 - mm);
  float den = d0 * s0 + d1 * s1v;
  float4 acc;
  acc.x = a0.x * s0 + a1.x * s1v;
  acc.y = a0.y * s0 + a1.y * s1v;
  acc.z = a0.z * s0 + a1.z * s1v;
  acc.w = a0.w * s0 + a1.w * s1v;

  float inv = 1.f / den;
  float4 o;
  o.x = acc.x * inv + bias[c + 0];
  o.y = acc.y * inv + bias[c + 1];
  o.z = acc.z * inv + bias[c + 2];
  o.w = acc.w * inv + bias[c + 3];
  o.x = o.x > 0.f ? o.x : __expf(o.x) - 1.f;          // ELU
  o.y = o.y > 0.f ? o.y : __expf(o.y) - 1.f;
  o.z = o.z > 0.f ? o.z : __expf(o.z) - 1.f;
  o.w = o.w > 0.f ? o.w : __expf(o.w) - 1.f;
  if constexpr (!FINAL) {
    uint2 pk;
    pk.x = (unsigned)f2bf(o.x) | ((unsigned)f2bf(o.y) << 16);
    pk.y = (unsigned)f2bf(o.z) | ((unsigned)f2bf(o.w) << 16);
    *(uint2*)(outb + (size_t)node * CT + c) = pk;
  } else {
    // fused out = elu(h3) @ Wout + bout ; reduce over the node's 16 lanes
    float p0 = o.x * Wout[(c + 0) * 2 + 0] + o.y * Wout[(c + 1) * 2 + 0]
             + o.z * Wout[(c + 2) * 2 + 0] + o.w * Wout[(c + 3) * 2 + 0];
    float p1 = o.x * Wout[(c + 0) * 2 + 1] + o.y * Wout[(c + 1) * 2 + 1]
             + o.z * Wout[(c + 2) * 2 + 1] + o.w * Wout[(c + 3) * 2 + 1];
#pragma unroll
    for (int off = 1; off < 16; off <<= 1) { p0 += __shfl_xor(p0, off); p1 += __shfl_xor(p1, off); }
    if (q == 0) { outf[node * 2 + 0] = p0 + bout[0]; outf[node * 2 + 1] = p1 + bout[1]; }
  }
}

extern "C" void kernel_launch(void* const* d_in, const int* in_sizes, int n_in,
                              void* d_out, int out_size, void* d_ws, size_t ws_size,
                              hipStream_t stream) {
  const float* x    = (const float*)d_in[0];
  const int*   ei   = (const int*)d_in[1];
  const float* W1   = (const float*)d_in[2];
  const float* as1  = (const float*)d_in[3];
  const float* ad1  = (const float*)d_in[4];
  const float* b1   = (const float*)d_in[5];
  const float* W2   = (const float*)d_in[6];
  const float* as2  = (const float*)d_in[7];
  const float* ad2  = (const float*)d_in[8];
  const float* b2   = (const float*)d_in[9];
  const float* W3   = (const float*)d_in[10];
  const float* as3  = (const float*)d_in[11];
  const float* ad3  = (const float*)d_in[12];
  const float* b3   = (const float*)d_in[13];
  const float* Wout = (const float*)d_in[14];
  const float* bout = (const float*)d_in[15];
  const int* srcp = ei;
  const int* dstp = ei + NE;

  char* p = (char*)d_ws;
  auto alloc = [&](size_t bytes) { char* r = p; p += (bytes + 255) & ~size_t(255); return r; };
  int*            rowptr  = (int*)alloc((size_t)(NN + 1) * 4);
  int*            counts  = (int*)alloc((size_t)NN * 4);
  int*            partial = (int*)alloc((size_t)NN * 4);
  int*            blksum  = (int*)alloc(256 * 4);
  int*            esrc    = (int*)alloc((size_t)ET * 4);
  int*            slots   = (int*)alloc((size_t)ET * 4);
  float*          asb     = (float*)alloc((size_t)NN * 8 * 4);
  float*          adb     = (float*)alloc((size_t)NN * 8 * 4);
  unsigned short* hfb     = (unsigned short*)alloc((size_t)NN * 128 * 2);   // bf16 gather table
  unsigned short* actb    = (unsigned short*)alloc((size_t)NN * 128 * 2);   // bf16 activations

  hipMemsetAsync(counts, 0, (size_t)NN * 4, stream);
  int gE = (ET + 255) / 256;
  int nb = (NN + SCAN_BLK - 1) / SCAN_BLK;   // 25 <= 256
  k_hist<<<gE, 256, 0, stream>>>(dstp, counts, slots);
  k_scan1<<<nb, 256, 0, stream>>>(counts, partial, blksum);
  k_scan2<<<1, 256, 0, stream>>>(blksum, nb);
  k_scan3<<<(NN + 255) / 256, 256, 0, stream>>>(partial, blksum, rowptr);
  k_scatter<<<gE, 256, 0, stream>>>(srcp, dstp, rowptr, slots, esrc);

  int gGemm = (NN + 63) / 64;
  // layer 1: 128 -> 8x16, concat, ELU
  k_gemm<128, false><<<gGemm, 256, 0, stream>>>(x, nullptr, W1, as1, ad1, hfb, asb, adb);
  k_aggregate<8, 16, false><<<(NN * 32 + 255) / 256, 256, 0, stream>>>(hfb, asb, adb, rowptr, esrc, b1, nullptr, nullptr, actb, nullptr);
  // layer 2
  k_gemm<128, true><<<gGemm, 256, 0, stream>>>(nullptr, actb, W2, as2, ad2, hfb, asb, adb);
  k_aggregate<8, 16, false><<<(NN * 32 + 255) / 256, 256, 0, stream>>>(hfb, asb, adb, rowptr, esrc, b2, nullptr, nullptr, actb, nullptr);
  // layer 3: 128 -> 1x64, mean(=identity), ELU, fused 64->2 output linear
  k_gemm<64, true><<<gGemm, 256, 0, stream>>>(nullptr, actb, W3, as3, ad3, hfb, asb, adb);
  k_aggregate<1, 64, true><<<(NN * 16 + 255) / 256, 256, 0, stream>>>(hfb, asb, adb, rowptr, esrc, b3, Wout, bout, nullptr, (float*)d_out);
}